// Round 1
// baseline (1664.486 us; speedup 1.0000x reference)
//
#include <hip/hip_runtime.h>
#include <math.h>

#define D_MODEL 512
#define NVAR    2048
#define J3      1536
#define NBATCH  8

// Tiled fp32 GEMM params: 128x128 tile, K-tile 16, 256 threads, 8x8 micro-tile
#define BM   128
#define BN   128
#define KT   16
#define TM   8
#define TN   8
#define NTHR 256

// ---------------------------------------------------------------------------
// K1: qkv[b][n][j] = sum_l x[b][l][n] * Wqkv[l][j] + bqkv[j]
//     A = x[b] viewed as [L=512][N=2048] (row l contiguous over n -> coalesced)
// ---------------------------------------------------------------------------
__global__ __launch_bounds__(NTHR)
void k_qkv(const float* __restrict__ x, const float* __restrict__ W,
           const float* __restrict__ bias, float* __restrict__ qkv, int b_start) {
    __shared__ float As[KT][BM];      // [l][n] direct load
    __shared__ float Bs[KT][BN];      // [l][j] direct load
    const int bz = blockIdx.z;
    const float* xb = x + (size_t)(b_start + bz) * D_MODEL * NVAR;
    float* qb = qkv + (size_t)bz * NVAR * J3;
    const int n0 = blockIdx.x * BM;
    const int j0 = blockIdx.y * BN;
    const int tid = threadIdx.x;
    const int tx = tid & 15, ty = tid >> 4;
    float acc[TM][TN] = {};
    const int ni = tid & 127, k0 = tid >> 7;
    for (int l0 = 0; l0 < D_MODEL; l0 += KT) {
#pragma unroll
        for (int s = 0; s < 8; ++s) {
            int kt = k0 + s * 2;
            As[kt][ni] = xb[(size_t)(l0 + kt) * NVAR + n0 + ni];
            Bs[kt][ni] = W[(size_t)(l0 + kt) * J3 + j0 + ni];
        }
        __syncthreads();
#pragma unroll
        for (int kt = 0; kt < KT; ++kt) {
            float a[TM], b[TN];
#pragma unroll
            for (int i = 0; i < TM; ++i) a[i] = As[kt][ty * TM + i];
#pragma unroll
            for (int j = 0; j < TN; ++j) b[j] = Bs[kt][tx * TN + j];
#pragma unroll
            for (int i = 0; i < TM; ++i)
#pragma unroll
                for (int j = 0; j < TN; ++j)
                    acc[i][j] += a[i] * b[j];
        }
        __syncthreads();
    }
#pragma unroll
    for (int i = 0; i < TM; ++i) {
        size_t n = (size_t)(n0 + ty * TM + i);
#pragma unroll
        for (int j = 0; j < TN; ++j) {
            int jj = j0 + tx * TN + j;
            qb[n * J3 + jj] = acc[i][j] + bias[jj];
        }
    }
}

// ---------------------------------------------------------------------------
// K2: S[nloc][m] = scale * sum_d q[n][d] * k[m][d]
//     q at qkv[n*J3 + d], k at qkv[m*J3 + 512 + d]; K-dim (d) contiguous
// ---------------------------------------------------------------------------
__global__ __launch_bounds__(NTHR)
void k_qk(const float* __restrict__ qkv, float* __restrict__ S, int nrow0, int rm) {
    __shared__ float Qs[KT][BM + 1];  // transposed store -> +1 pad
    __shared__ float Ks[KT][BN + 1];
    const int bz = blockIdx.z;
    const float* qb = qkv + (size_t)bz * NVAR * J3;
    float* Sb = S + (size_t)bz * (size_t)rm * NVAR;
    const int n0 = nrow0 + blockIdx.x * BM;
    const int m0 = blockIdx.y * BN;
    const int tid = threadIdx.x;
    const int tx = tid & 15, ty = tid >> 4;
    float acc[TM][TN] = {};
    const int c = tid & 15, r = tid >> 4;
    for (int d0 = 0; d0 < D_MODEL; d0 += KT) {
#pragma unroll
        for (int s = 0; s < 8; ++s) {
            int rr = r + s * 16;
            Qs[c][rr] = qb[(size_t)(n0 + rr) * J3 + d0 + c];
            Ks[c][rr] = qb[(size_t)(m0 + rr) * J3 + 512 + d0 + c];
        }
        __syncthreads();
#pragma unroll
        for (int kt = 0; kt < KT; ++kt) {
            float a[TM], b[TN];
#pragma unroll
            for (int i = 0; i < TM; ++i) a[i] = Qs[kt][ty * TM + i];
#pragma unroll
            for (int j = 0; j < TN; ++j) b[j] = Ks[kt][tx * TN + j];
#pragma unroll
            for (int i = 0; i < TM; ++i)
#pragma unroll
                for (int j = 0; j < TN; ++j)
                    acc[i][j] += a[i] * b[j];
        }
        __syncthreads();
    }
    const float scale = 0.044194173824159216f;  // 1/sqrt(512)
#pragma unroll
    for (int i = 0; i < TM; ++i) {
        size_t row = (size_t)(n0 - nrow0 + ty * TM + i);
#pragma unroll
        for (int j = 0; j < TN; ++j) {
            Sb[row * NVAR + m0 + tx * TN + j] = acc[i][j] * scale;
        }
    }
}

// ---------------------------------------------------------------------------
// K3: row softmax over S rows (length NVAR = 2048), one block per row
// ---------------------------------------------------------------------------
__global__ __launch_bounds__(256)
void k_softmax(float* __restrict__ S, int rm) {
    float* row = S + (size_t)blockIdx.y * (size_t)rm * NVAR + (size_t)blockIdx.x * NVAR;
    const int tid = threadIdx.x;
    float v[8];
    float m = -3.0e38f;
#pragma unroll
    for (int i = 0; i < 8; ++i) { v[i] = row[tid + (i << 8)]; m = fmaxf(m, v[i]); }
#pragma unroll
    for (int off = 32; off > 0; off >>= 1) m = fmaxf(m, __shfl_xor(m, off));
    __shared__ float red[4];
    __shared__ float red2[4];
    const int lane = tid & 63, wid = tid >> 6;
    if (!lane) red[wid] = m;
    __syncthreads();
    m = fmaxf(fmaxf(red[0], red[1]), fmaxf(red[2], red[3]));
    float s = 0.f;
#pragma unroll
    for (int i = 0; i < 8; ++i) { v[i] = __expf(v[i] - m); s += v[i]; }
#pragma unroll
    for (int off = 32; off > 0; off >>= 1) s += __shfl_xor(s, off);
    if (!lane) red2[wid] = s;
    __syncthreads();
    s = red2[0] + red2[1] + red2[2] + red2[3];
    float inv = 1.0f / s;
#pragma unroll
    for (int i = 0; i < 8; ++i) row[tid + (i << 8)] = v[i] * inv;
}

// ---------------------------------------------------------------------------
// K4: O[n][d] = sum_m P[nloc][m] * v[m][d];  v at qkv[m*J3 + 1024 + d]
// ---------------------------------------------------------------------------
__global__ __launch_bounds__(NTHR)
void k_pv(const float* __restrict__ S, const float* __restrict__ qkv,
          float* __restrict__ O, int nrow0, int rm) {
    __shared__ float Ps[KT][BM + 1];  // transposed store (A has K contiguous)
    __shared__ float Vs[KT][BN];      // direct store
    const int bz = blockIdx.z;
    const float* Sb = S + (size_t)bz * (size_t)rm * NVAR;
    const float* qb = qkv + (size_t)bz * NVAR * J3;
    float* Ob = O + (size_t)bz * NVAR * D_MODEL;
    const int nl0 = blockIdx.x * BM;   // local row within chunk
    const int d0_ = blockIdx.y * BN;
    const int tid = threadIdx.x;
    const int tx = tid & 15, ty = tid >> 4;
    float acc[TM][TN] = {};
    const int c = tid & 15, r = tid >> 4;
    const int ni = tid & 127, k0 = tid >> 7;
    for (int m0 = 0; m0 < NVAR; m0 += KT) {
#pragma unroll
        for (int s = 0; s < 8; ++s) {
            int rr = r + s * 16;
            Ps[c][rr] = Sb[(size_t)(nl0 + rr) * NVAR + m0 + c];
        }
#pragma unroll
        for (int s = 0; s < 8; ++s) {
            int kt = k0 + s * 2;
            Vs[kt][ni] = qb[(size_t)(m0 + kt) * J3 + 1024 + d0_ + ni];
        }
        __syncthreads();
#pragma unroll
        for (int kt = 0; kt < KT; ++kt) {
            float a[TM], b[TN];
#pragma unroll
            for (int i = 0; i < TM; ++i) a[i] = Ps[kt][ty * TM + i];
#pragma unroll
            for (int j = 0; j < TN; ++j) b[j] = Vs[kt][tx * TN + j];
#pragma unroll
            for (int i = 0; i < TM; ++i)
#pragma unroll
                for (int j = 0; j < TN; ++j)
                    acc[i][j] += a[i] * b[j];
        }
        __syncthreads();
    }
#pragma unroll
    for (int i = 0; i < TM; ++i) {
        size_t n = (size_t)(nrow0 + nl0 + ty * TM + i);
#pragma unroll
        for (int j = 0; j < TN; ++j) {
            Ob[n * D_MODEL + d0_ + tx * TN + j] = acc[i][j];
        }
    }
}

// ---------------------------------------------------------------------------
// K5: out[b][l][n] = sum_d O[n][d] * Wproj[d][l] + bproj[l]  (transposed store)
//     tx indexes n (fast-varying store dim) for coalescing
// ---------------------------------------------------------------------------
__global__ __launch_bounds__(NTHR)
void k_proj(const float* __restrict__ O, const float* __restrict__ Wp,
            const float* __restrict__ bp, float* __restrict__ out, int b_start) {
    __shared__ float Os[KT][BM + 1];  // transposed store (A has K contiguous)
    __shared__ float Ws[KT][BN];
    const int bz = blockIdx.z;
    const float* Ob = O + (size_t)bz * NVAR * D_MODEL;
    float* outb = out + (size_t)(b_start + bz) * D_MODEL * NVAR;
    const int n0 = blockIdx.x * BM;   // over NVAR
    const int l0 = blockIdx.y * BN;   // over D_MODEL
    const int tid = threadIdx.x;
    const int tx = tid & 15, ty = tid >> 4;  // tx -> n, ty -> l
    float acc[TM][TN] = {};                  // [n-sub][l-sub]
    const int c = tid & 15, r = tid >> 4;
    const int ni = tid & 127, k0 = tid >> 7;
    for (int d0 = 0; d0 < D_MODEL; d0 += KT) {
#pragma unroll
        for (int s = 0; s < 8; ++s) {
            int rr = r + s * 16;
            Os[c][rr] = Ob[(size_t)(n0 + rr) * D_MODEL + d0 + c];
        }
#pragma unroll
        for (int s = 0; s < 8; ++s) {
            int kt = k0 + s * 2;
            Ws[kt][ni] = Wp[(size_t)(d0 + kt) * D_MODEL + l0 + ni];
        }
        __syncthreads();
#pragma unroll
        for (int kt = 0; kt < KT; ++kt) {
            float a[TM], b[TN];
#pragma unroll
            for (int i = 0; i < TM; ++i) a[i] = Os[kt][tx * TM + i];   // n
#pragma unroll
            for (int j = 0; j < TN; ++j) b[j] = Ws[kt][ty * TN + j];   // l
#pragma unroll
            for (int i = 0; i < TM; ++i)
#pragma unroll
                for (int j = 0; j < TN; ++j)
                    acc[i][j] += a[i] * b[j];
        }
        __syncthreads();
    }
#pragma unroll
    for (int j = 0; j < TN; ++j) {
        int l = l0 + ty * TN + j;
        float bb = bp[l];
#pragma unroll
        for (int i = 0; i < TM; ++i) {
            outb[(size_t)l * NVAR + n0 + tx * TM + i] = acc[i][j] + bb;
        }
    }
}

// ---------------------------------------------------------------------------
extern "C" void kernel_launch(void* const* d_in, const int* in_sizes, int n_in,
                              void* d_out, int out_size, void* d_ws, size_t ws_size,
                              hipStream_t stream) {
    const float* x     = (const float*)d_in[0];
    const float* Wqkv  = (const float*)d_in[1];
    const float* bqkv  = (const float*)d_in[2];
    const float* Wproj = (const float*)d_in[3];
    const float* bproj = (const float*)d_in[4];
    float* out = (float*)d_out;

    const size_t qkv_f = (size_t)NVAR * J3;       // floats per batch
    const size_t o_f   = (size_t)NVAR * D_MODEL;  // floats per batch

    auto need = [&](int nb, int rmv) -> size_t {
        return ((size_t)nb * (qkv_f + o_f) + (size_t)nb * (size_t)rmv * NVAR) * sizeof(float);
    };

    int nb, RM;
    if (ws_size >= need(NBATCH, NVAR)) {
        nb = NBATCH; RM = NVAR;                  // full-parallel: 256 MiB ws
    } else {
        nb = 1; RM = NVAR;                       // per-batch, shrink S row-chunk to fit
        while (RM > BM && ws_size < need(1, RM)) RM >>= 1;
    }

    for (int b0 = 0; b0 < NBATCH; b0 += nb) {
        float* qkv = (float*)d_ws;
        float* O   = qkv + (size_t)nb * qkv_f;
        float* S   = O + (size_t)nb * o_f;

        k_qkv<<<dim3(NVAR / BM, J3 / BN, nb), NTHR, 0, stream>>>(x, Wqkv, bqkv, qkv, b0);
        for (int r0 = 0; r0 < NVAR; r0 += RM) {
            k_qk<<<dim3(RM / BM, NVAR / BN, nb), NTHR, 0, stream>>>(qkv, S, r0, RM);
            k_softmax<<<dim3(RM, nb), 256, 0, stream>>>(S, RM);
            k_pv<<<dim3(RM / BM, D_MODEL / BN, nb), NTHR, 0, stream>>>(S, qkv, O, r0, RM);
        }
        k_proj<<<dim3(NVAR / BM, D_MODEL / BN, nb), NTHR, 0, stream>>>(O, Wproj, bproj, out, b0);
    }
}

// Round 2
// 197.389 us; speedup vs baseline: 8.4325x; 8.4325x over previous
//
#include <hip/hip_runtime.h>

#define NVAR 2048
#define DM   512
#define J3   1536

typedef _Float16 f16;
typedef _Float16 f16x8 __attribute__((ext_vector_type(8)));
typedef _Float16 f16x4 __attribute__((ext_vector_type(4)));
typedef float    f32x4 __attribute__((ext_vector_type(4)));

// ---------------------------------------------------------------------------
// Transpose fp32 [R][C] -> f16 [C][R] (per grid.z batch)
// ---------------------------------------------------------------------------
__global__ __launch_bounds__(256)
void k_tr(const float* __restrict__ src, f16* __restrict__ dst,
          int R, int C, long bsSrc, long bsDst) {
    __shared__ float t[64][65];
    const float* s = src + (size_t)blockIdx.z * bsSrc;
    f16* d = dst + (size_t)blockIdx.z * bsDst;
    const int c0 = blockIdx.x * 64, r0 = blockIdx.y * 64;
    const int tx = threadIdx.x & 63, w = threadIdx.x >> 6;
#pragma unroll
    for (int i = 0; i < 16; ++i) {
        int r = w * 16 + i;
        t[r][tx] = s[(size_t)(r0 + r) * C + c0 + tx];
    }
    __syncthreads();
#pragma unroll
    for (int i = 0; i < 16; ++i) {
        int c = w * 16 + i;
        d[(size_t)(c0 + c) * R + r0 + tx] = (f16)t[tx][c];
    }
}

// ---------------------------------------------------------------------------
// f16 MFMA GEMM, NT form: A [M][K] f16 rows K-contiguous (lda),
//                         B [N][K] f16 rows K-contiguous (ldb).
// 128x128 tile, BK=64, 4 waves (2x2), wave tile 64x64 (4x4 of 16x16x32).
// global_load_lds(16B) staging with XOR-swizzled source (LDS stays linear),
// swizzled ds_read_b128 -> conflict-free.
// MODE 0: qkv epilogue (+bias, split j into q/k/vT, vT transposed store)
// MODE 1: S = acc*scale -> f16
// MODE 2: O = acc -> f16
// MODE 3: out = acc + bias[row] -> fp32 (C[l][n], n contiguous)
// ---------------------------------------------------------------------------
template<int MODE>
__global__ __launch_bounds__(256)
void gemm_f16(const f16* __restrict__ A, const f16* __restrict__ B,
              long bsA, long bsB, int lda, int ldb, int K,
              const float* __restrict__ bias, float scale,
              f16* __restrict__ out0, f16* __restrict__ out1, f16* __restrict__ out2,
              float* __restrict__ outf) {
    __shared__ f16 sA[128 * 64];
    __shared__ f16 sB[128 * 64];
    const int tid  = threadIdx.x;
    const int lane = tid & 63;
    const int w    = __builtin_amdgcn_readfirstlane(tid >> 6);
    const int wm   = (w >> 1) * 64;   // wave row offset in tile
    const int wn   = (w & 1) * 64;    // wave col offset in tile
    const int z    = blockIdx.z;

    const f16* Ab = A + (size_t)z * bsA + (size_t)blockIdx.x * 128 * lda;
    const f16* Bb = B + (size_t)z * bsB + (size_t)blockIdx.y * 128 * ldb;

    // Staging: tile = 128 rows x 64 f16 = 1024 slots of 16B, 8 slots/row.
    // LDS slot (row, s') holds global (row, s = s' ^ (row&7)).
    size_t srcA[4], srcB[4];
#pragma unroll
    for (int i = 0; i < 4; ++i) {
        int slot = i * 256 + tid;
        int row  = slot >> 3;
        int s    = (slot & 7) ^ (row & 7);
        srcA[i] = (size_t)row * lda + s * 8;
        srcB[i] = (size_t)row * ldb + s * 8;
    }

    f32x4 acc[4][4] = {};

    for (int k0 = 0; k0 < K; k0 += 64) {
        __syncthreads();   // previous tile consumed
#pragma unroll
        for (int i = 0; i < 4; ++i) {
            __builtin_amdgcn_global_load_lds(
                (const __attribute__((address_space(1))) void*)(Ab + srcA[i] + k0),
                (__attribute__((address_space(3))) void*)(sA + i * 2048 + w * 512),
                16, 0, 0);
            __builtin_amdgcn_global_load_lds(
                (const __attribute__((address_space(1))) void*)(Bb + srcB[i] + k0),
                (__attribute__((address_space(3))) void*)(sB + i * 2048 + w * 512),
                16, 0, 0);
        }
        __syncthreads();   // compiler drains vmcnt before barrier
#pragma unroll
        for (int kh = 0; kh < 2; ++kh) {
            f16x8 av[4], bv[4];
#pragma unroll
            for (int mi = 0; mi < 4; ++mi) {
                int r = wm + mi * 16 + (lane & 15);
                int s = (kh * 4 + (lane >> 4)) ^ (r & 7);
                av[mi] = *(const f16x8*)(sA + r * 64 + s * 8);
            }
#pragma unroll
            for (int nj = 0; nj < 4; ++nj) {
                int r = wn + nj * 16 + (lane & 15);
                int s = (kh * 4 + (lane >> 4)) ^ (r & 7);
                bv[nj] = *(const f16x8*)(sB + r * 64 + s * 8);
            }
#pragma unroll
            for (int mi = 0; mi < 4; ++mi)
#pragma unroll
                for (int nj = 0; nj < 4; ++nj)
                    acc[mi][nj] = __builtin_amdgcn_mfma_f32_16x16x32_f16(
                        av[mi], bv[nj], acc[mi][nj], 0, 0, 0);
        }
    }

    // Epilogue.  C/D frag: col = lane&15, row = (lane>>4)*4 + r  [m89-verified]
    const int row0 = blockIdx.x * 128 + wm + (lane >> 4) * 4;
    const int col0 = blockIdx.y * 128 + wn + (lane & 15);

    if (MODE == 0) {
        const int seg = (blockIdx.y * 128) >> 9;  // 0=q 1=k 2=v, uniform per block
#pragma unroll
        for (int nj = 0; nj < 4; ++nj) {
            int j = col0 + nj * 16;
            float bb = bias[j];
            if (seg == 2) {
#pragma unroll
                for (int mi = 0; mi < 4; ++mi) {
                    int n = row0 + mi * 16;
                    f16x4 vv;
#pragma unroll
                    for (int r = 0; r < 4; ++r) vv[r] = (f16)(acc[mi][nj][r] + bb);
                    *(f16x4*)(out2 + ((size_t)z * DM + (j - 1024)) * NVAR + n) = vv;
                }
            } else {
                f16* dst = (seg == 0) ? out0 : out1;
                int jj = (seg == 0) ? j : j - 512;
#pragma unroll
                for (int mi = 0; mi < 4; ++mi) {
                    int n = row0 + mi * 16;
#pragma unroll
                    for (int r = 0; r < 4; ++r)
                        dst[((size_t)z * NVAR + n + r) * DM + jj] =
                            (f16)(acc[mi][nj][r] + bb);
                }
            }
        }
    } else if (MODE == 1) {
#pragma unroll
        for (int mi = 0; mi < 4; ++mi)
#pragma unroll
            for (int nj = 0; nj < 4; ++nj)
#pragma unroll
                for (int r = 0; r < 4; ++r)
                    out0[((size_t)z * NVAR + row0 + mi * 16 + r) * NVAR + col0 + nj * 16] =
                        (f16)(acc[mi][nj][r] * scale);
    } else if (MODE == 2) {
#pragma unroll
        for (int mi = 0; mi < 4; ++mi)
#pragma unroll
            for (int nj = 0; nj < 4; ++nj)
#pragma unroll
                for (int r = 0; r < 4; ++r)
                    out0[((size_t)z * NVAR + row0 + mi * 16 + r) * DM + col0 + nj * 16] =
                        (f16)acc[mi][nj][r];
    } else {
#pragma unroll
        for (int mi = 0; mi < 4; ++mi) {
#pragma unroll
            for (int r = 0; r < 4; ++r) {
                int l = row0 + mi * 16 + r;
                float bb = bias[l];
#pragma unroll
                for (int nj = 0; nj < 4; ++nj)
                    outf[((size_t)z * DM + l) * NVAR + col0 + nj * 16] =
                        acc[mi][nj][r] + bb;
            }
        }
    }
}

// ---------------------------------------------------------------------------
// In-place row softmax on f16 S rows of length 2048 (fp32 math inside)
// ---------------------------------------------------------------------------
__global__ __launch_bounds__(256)
void k_sm(f16* __restrict__ S) {
    f16* row = S + ((size_t)blockIdx.y * NVAR + blockIdx.x) * NVAR;
    const int tid = threadIdx.x;
    f16x8 v8 = *(const f16x8*)(row + tid * 8);
    float v[8];
    float m = -3.0e38f;
#pragma unroll
    for (int i = 0; i < 8; ++i) { v[i] = (float)v8[i]; m = fmaxf(m, v[i]); }
#pragma unroll
    for (int off = 32; off > 0; off >>= 1) m = fmaxf(m, __shfl_xor(m, off));
    __shared__ float red[4], red2[4];
    const int lane = tid & 63, wid = tid >> 6;
    if (!lane) red[wid] = m;
    __syncthreads();
    m = fmaxf(fmaxf(red[0], red[1]), fmaxf(red[2], red[3]));
    float s = 0.f;
#pragma unroll
    for (int i = 0; i < 8; ++i) { v[i] = __expf(v[i] - m); s += v[i]; }
#pragma unroll
    for (int off = 32; off > 0; off >>= 1) s += __shfl_xor(s, off);
    if (!lane) red2[wid] = s;
    __syncthreads();
    s = red2[0] + red2[1] + red2[2] + red2[3];
    float inv = 1.0f / s;
#pragma unroll
    for (int i = 0; i < 8; ++i) v8[i] = (f16)(v[i] * inv);
    *(f16x8*)(row + tid * 8) = v8;
}

// ---------------------------------------------------------------------------
extern "C" void kernel_launch(void* const* d_in, const int* in_sizes, int n_in,
                              void* d_out, int out_size, void* d_ws, size_t ws_size,
                              hipStream_t stream) {
    const float* x     = (const float*)d_in[0];
    const float* Wqkv  = (const float*)d_in[1];
    const float* bqkv  = (const float*)d_in[2];
    const float* Wproj = (const float*)d_in[3];
    const float* bproj = (const float*)d_in[4];
    float* out = (float*)d_out;

    const size_t PB = (size_t)NVAR * DM;          // 2048*512 per batch
    f16* xT  = (f16*)d_ws;                        // [b][n][l]   8*PB
    f16* q   = xT + 8 * PB;                       // [b][n][d]
    f16* kk  = q  + 8 * PB;                       // [b][m][d]
    f16* vT  = kk + 8 * PB;                       // [b][d][m]
    f16* S   = vT + 8 * PB;                       // [b][n][m]   8*2048*2048
    f16* O   = S  + (size_t)8 * NVAR * NVAR;      // [b][n][d]
    f16* WqT = O  + 8 * PB;                       // [j][l]  1536*512
    f16* WpT = WqT + (size_t)J3 * DM;             // [l][d]  512*512

    // conversions / transposes
    k_tr<<<dim3(NVAR / 64, DM / 64, 8), 256, 0, stream>>>(
        x, xT, DM, NVAR, (long)DM * NVAR, (long)NVAR * DM);
    k_tr<<<dim3(J3 / 64, DM / 64, 1), 256, 0, stream>>>(Wqkv, WqT, DM, J3, 0, 0);
    k_tr<<<dim3(DM / 64, DM / 64, 1), 256, 0, stream>>>(Wproj, WpT, DM, DM, 0, 0);

    // qkv = xT @ WqkvT^T + b   (M=2048, N=1536, K=512)
    gemm_f16<0><<<dim3(16, 12, 8), 256, 0, stream>>>(
        xT, WqT, (long)NVAR * DM, 0, DM, DM, DM, bqkv, 1.f, q, kk, vT, nullptr);

    // S = q @ k^T * scale       (M=2048, N=2048, K=512)
    gemm_f16<1><<<dim3(16, 16, 8), 256, 0, stream>>>(
        q, kk, (long)NVAR * DM, (long)NVAR * DM, DM, DM, DM,
        nullptr, 0.044194173824159216f, S, nullptr, nullptr, nullptr);

    // softmax in place
    k_sm<<<dim3(NVAR, 8), 256, 0, stream>>>(S);

    // O = P @ vT^T              (M=2048, N=512, K=2048)
    gemm_f16<2><<<dim3(16, 4, 8), 256, 0, stream>>>(
        S, vT, (long)NVAR * NVAR, (long)DM * NVAR, NVAR, NVAR, NVAR,
        nullptr, 1.f, O, nullptr, nullptr, nullptr);

    // out[l][n] = WprojT @ O^T + b  (M=512, N=2048, K=512)
    gemm_f16<3><<<dim3(4, 16, 8), 256, 0, stream>>>(
        WpT, O, 0, (long)NVAR * DM, DM, DM, DM,
        bproj, 1.f, nullptr, nullptr, nullptr, out);
}